// Round 1
// baseline (883.814 us; speedup 1.0000x reference)
//
#include <hip/hip_runtime.h>
#include <cstdint>
#include <cstddef>

typedef unsigned short u16;
typedef __attribute__((ext_vector_type(8))) short short8;
typedef __attribute__((ext_vector_type(4))) float f32x4;

#define T_SEQ 2048
#define DM    2048
#define NHEAD 16
#define NKV   4
#define HD    128
#define NEGBIG (-3.0e38f)

__device__ __forceinline__ u16 f2bf(float f) {
  union { float f; unsigned u; } c; c.f = f;
  return (u16)((c.u + 0x7fffu + ((c.u >> 16) & 1u)) >> 16);
}
__device__ __forceinline__ float bf2f(u16 b) {
  union { float f; unsigned u; } c; c.u = ((unsigned)b) << 16;
  return c.f;
}
__device__ __forceinline__ void gl_lds16(const u16* g, u16* l) {
  __builtin_amdgcn_global_load_lds(
      (const __attribute__((address_space(1))) void*)g,
      (__attribute__((address_space(3))) void*)l, 16, 0, 0);
}

// ---------------- cast fp32 -> bf16 ----------------
__global__ void castk(const float* __restrict__ src, u16* __restrict__ dst, int n) {
  int i = (blockIdx.x * 256 + threadIdx.x) * 4;
  if (i >= n) return;
  float4 v = *(const float4*)(src + i);
  dst[i + 0] = f2bf(v.x);
  dst[i + 1] = f2bf(v.y);
  dst[i + 2] = f2bf(v.z);
  dst[i + 3] = f2bf(v.w);
}

// ---------------- RoPE in-place on [rows, HD] bf16 ----------------
__global__ void ropek(u16* __restrict__ buf, int rows) {
  int idx = blockIdx.x * 256 + threadIdx.x;
  if (idx >= rows * 64) return;
  int r = idx >> 6, i = idx & 63;
  int t = r & (T_SEQ - 1);
  // inv_freq[i] = 1e6^(-i/64) = exp(-i * ln(1e6)/64)
  float inv = expf(-0.215867352496f * (float)i);
  float ang = (float)t * inv;
  float c = cosf(ang), s = sinf(ang);
  size_t base = (size_t)r * HD + i;
  float x1 = bf2f(buf[base]), x2 = bf2f(buf[base + 64]);
  buf[base]      = f2bf(x1 * c - x2 * s);
  buf[base + 64] = f2bf(x2 * c + x1 * s);
}

// ---------------- GEMM: C[M,N] = A[M,K] @ Bm[N,K]^T  (bf16 in, MFMA) -------
// MODE 0: fp32 plain row-major out
// MODE 1: bf16 out scattered to [B, n_heads, T, HD]
// MODE 2: bf16 out scattered to [B, n_heads, HD, T]  (V transposed)
template <int MODE>
__global__ __launch_bounds__(256) void gemm_bt(
    const u16* __restrict__ A, const u16* __restrict__ Bm, void* __restrict__ Out,
    int M, int N, int K, int n_heads) {
  __shared__ __align__(16) u16 As[128 * 32];
  __shared__ __align__(16) u16 Bs[128 * 32];
  const int tid = threadIdx.x;
  const int w = tid >> 6, l = tid & 63;
  const int lm = l & 15, q = l >> 4;
  const int m0 = blockIdx.y * 128, n0 = blockIdx.x * 128;
  const int mq = w & 1, nq = w >> 1;
  const u16* Ab = A + (size_t)m0 * K;
  const u16* Bb = Bm + (size_t)n0 * K;

  f32x4 acc[4][4] = {};

  for (int k0 = 0; k0 < K; k0 += 32) {
#pragma unroll
    for (int c = 0; c < 2; ++c) {
      int s = c * 256 + w * 64 + l;  // 16B slot id; row = s>>2, kq = s&3
      int row = s >> 2, kq = s & 3;
      gl_lds16(Ab + (size_t)row * K + k0 + kq * 8, As + s * 8);
      gl_lds16(Bb + (size_t)row * K + k0 + kq * 8, Bs + s * 8);
    }
    __syncthreads();
    short8 af[4], bf[4];
#pragma unroll
    for (int i = 0; i < 4; ++i) {
      af[i] = *(const short8*)(As + (mq * 64 + i * 16 + lm) * 32 + q * 8);
      bf[i] = *(const short8*)(Bs + (nq * 64 + i * 16 + lm) * 32 + q * 8);
    }
#pragma unroll
    for (int i = 0; i < 4; ++i)
#pragma unroll
      for (int j = 0; j < 4; ++j)
        acc[i][j] = __builtin_amdgcn_mfma_f32_16x16x32_bf16(af[i], bf[j], acc[i][j], 0, 0, 0);
    __syncthreads();
  }

#pragma unroll
  for (int i = 0; i < 4; ++i)
#pragma unroll
    for (int j = 0; j < 4; ++j)
#pragma unroll
      for (int r = 0; r < 4; ++r) {
        int m = m0 + mq * 64 + i * 16 + q * 4 + r;
        int n = n0 + nq * 64 + j * 16 + lm;
        float v = acc[i][j][r];
        if constexpr (MODE == 0) {
          ((float*)Out)[(size_t)m * N + n] = v;
        } else {
          int b = m >> 11, t = m & (T_SEQ - 1);
          int h = n >> 7, d = n & (HD - 1);
          if constexpr (MODE == 1)
            ((u16*)Out)[(((size_t)(b * n_heads + h)) * T_SEQ + t) * HD + d] = f2bf(v);
          else
            ((u16*)Out)[(((size_t)(b * n_heads + h)) * HD + d) * T_SEQ + t] = f2bf(v);
        }
      }
}

// ---------------- flash attention ----------------
// grid: (T/64, B*NHEAD), block 256. Q:[B,NH,T,HD] K:[B,NKV,T,HD] V:[B,NKV,HD,T]
__global__ __launch_bounds__(256) void attnk(
    const u16* __restrict__ Q, const u16* __restrict__ Kh,
    const u16* __restrict__ Vt, u16* __restrict__ Oa) {
  __shared__ __align__(16) u16 Pl[4 * 16 * 64];
  const int tid = threadIdx.x;
  const int w = tid >> 6, l = tid & 63, lm = l & 15, q = l >> 4;
  const int bh = blockIdx.y, b = bh >> 4, h = bh & 15, kvh = h >> 2;
  const int q0 = ((int)gridDim.x - 1 - (int)blockIdx.x) * 64;  // heavy blocks first
  const int tb = q0 + w * 16;
  const u16* Qb = Q + (((size_t)(b * NHEAD + h)) * T_SEQ + tb) * HD;
  const u16* Kb = Kh + ((size_t)(b * NKV + kvh)) * T_SEQ * HD;
  const u16* Vb = Vt + ((size_t)(b * NKV + kvh)) * HD * T_SEQ;
  u16* Pw = Pl + w * 16 * 64;

  short8 qa[4];
#pragma unroll
  for (int ks = 0; ks < 4; ++ks)
    qa[ks] = *(const short8*)(Qb + (size_t)lm * HD + ks * 32 + q * 8);

  float m_i[4] = {NEGBIG, NEGBIG, NEGBIG, NEGBIG};
  float l_i[4] = {0.f, 0.f, 0.f, 0.f};
  f32x4 oacc[8] = {};
  const float scale = 0.08838834764831845f;  // 1/sqrt(128)
  const int nst = q0 / 64 + 1;

  for (int st = 0; st < nst; ++st) {
    const int s0 = st * 64;
    f32x4 sacc[4] = {};
#pragma unroll
    for (int ks = 0; ks < 4; ++ks) {
#pragma unroll
      for (int nt = 0; nt < 4; ++nt) {
        short8 kb = *(const short8*)(Kb + ((size_t)(s0 + nt * 16 + lm)) * HD + ks * 32 + q * 8);
        sacc[nt] = __builtin_amdgcn_mfma_f32_16x16x32_bf16(qa[ks], kb, sacc[nt], 0, 0, 0);
      }
    }
#pragma unroll
    for (int j = 0; j < 4; ++j) {
      const int t = tb + q * 4 + j;
      float pj[4];
      float mx = NEGBIG;
#pragma unroll
      for (int nt = 0; nt < 4; ++nt) {
        int s = s0 + nt * 16 + lm;
        float v = sacc[nt][j] * scale;
        pj[nt] = (s > t) ? NEGBIG : v;
        mx = fmaxf(mx, pj[nt]);
      }
#pragma unroll
      for (int d = 1; d < 16; d <<= 1) mx = fmaxf(mx, __shfl_xor(mx, d, 64));
      float mnew = fmaxf(m_i[j], mx);
      float alpha = expf(m_i[j] - mnew);
      float sum = 0.f;
#pragma unroll
      for (int nt = 0; nt < 4; ++nt) {
        float p = expf(pj[nt] - mnew);
        sum += p;
        Pw[(q * 4 + j) * 64 + nt * 16 + lm] = f2bf(p);
      }
#pragma unroll
      for (int d = 1; d < 16; d <<= 1) sum += __shfl_xor(sum, d, 64);
      m_i[j] = mnew;
      l_i[j] = alpha * l_i[j] + sum;
#pragma unroll
      for (int nt8 = 0; nt8 < 8; ++nt8) oacc[nt8][j] *= alpha;
    }
    __syncthreads();
#pragma unroll
    for (int ks = 0; ks < 2; ++ks) {
      short8 pa = *(const short8*)(Pw + lm * 64 + ks * 32 + q * 8);
#pragma unroll
      for (int nt8 = 0; nt8 < 8; ++nt8) {
        short8 vb = *(const short8*)(Vb + ((size_t)(nt8 * 16 + lm)) * T_SEQ + s0 + ks * 32 + q * 8);
        oacc[nt8] = __builtin_amdgcn_mfma_f32_16x16x32_bf16(pa, vb, oacc[nt8], 0, 0, 0);
      }
    }
    __syncthreads();
  }

#pragma unroll
  for (int j = 0; j < 4; ++j) {
    const int t = tb + q * 4 + j;
    float inv = 1.0f / l_i[j];
#pragma unroll
    for (int nt8 = 0; nt8 < 8; ++nt8)
      Oa[((size_t)(b * T_SEQ + t)) * (NHEAD * HD) + h * HD + nt8 * 16 + lm] =
          f2bf(oacc[nt8][j] * inv);
  }
}

extern "C" void kernel_launch(void* const* d_in, const int* in_sizes, int n_in,
                              void* d_out, int out_size, void* d_ws, size_t ws_size,
                              hipStream_t stream) {
  const float* x  = (const float*)d_in[0];
  const float* wq = (const float*)d_in[1];
  const float* wk = (const float*)d_in[2];
  const float* wv = (const float*)d_in[3];
  const float* wo = (const float*)d_in[4];
  float* out = (float*)d_out;

  // workspace layout (u16 elements). Ab aliases xb (xb dead after V-proj).
  u16* ws  = (u16*)d_ws;
  u16* xb  = ws;                      // 8M elems  (x bf16)  [later: attn out]
  u16* wqb = xb  + (8u << 20);        // 4M
  u16* wkb = wqb + (4u << 20);        // 1M
  u16* wvb = wkb + (1u << 20);        // 1M
  u16* wob = wvb + (1u << 20);        // 4M
  u16* Qb  = wob + (4u << 20);        // 8M
  u16* Kb  = Qb  + (8u << 20);        // 2M
  u16* Vtb = Kb  + (2u << 20);        // 2M
  u16* Ab  = xb;                      // alias: 8M  (total 30M elems = 60 MB)

  castk<<<8192, 256, 0, stream>>>(x,  xb,  8 << 20);
  castk<<<4096, 256, 0, stream>>>(wq, wqb, 4 << 20);
  castk<<<1024, 256, 0, stream>>>(wk, wkb, 1 << 20);
  castk<<<1024, 256, 0, stream>>>(wv, wvb, 1 << 20);
  castk<<<4096, 256, 0, stream>>>(wo, wob, 4 << 20);

  // projections
  gemm_bt<1><<<dim3(16, 32), 256, 0, stream>>>(xb, wqb, Qb,  4096, 2048, 2048, NHEAD);
  gemm_bt<1><<<dim3(4, 32),  256, 0, stream>>>(xb, wkb, Kb,  4096, 512,  2048, NKV);
  gemm_bt<2><<<dim3(4, 32),  256, 0, stream>>>(xb, wvb, Vtb, 4096, 512,  2048, NKV);

  // RoPE on Q and K
  ropek<<<16384, 256, 0, stream>>>(Qb, 2 * NHEAD * T_SEQ);
  ropek<<<4096,  256, 0, stream>>>(Kb, 2 * NKV * T_SEQ);

  // attention
  attnk<<<dim3(32, 32), 256, 0, stream>>>(Qb, Kb, Vtb, Ab);

  // output projection -> fp32 d_out
  gemm_bt<0><<<dim3(16, 32), 256, 0, stream>>>(Ab, wob, out, 4096, 2048, 2048, 0);
}

// Round 3
// 485.263 us; speedup vs baseline: 1.8213x; 1.8213x over previous
//
#include <hip/hip_runtime.h>
#include <cstdint>
#include <cstddef>

typedef unsigned short u16;
typedef unsigned long long u64;
typedef __attribute__((ext_vector_type(8))) short short8;
typedef __attribute__((ext_vector_type(4))) float f32x4;

#define T_SEQ 2048
#define DM    2048
#define NHEAD 16
#define NKV   4
#define HD    128
#define NEGBIG (-3.0e38f)

__device__ __forceinline__ u16 f2bf(float f) {
  union { float f; unsigned u; } c; c.f = f;
  return (u16)((c.u + 0x7fffu + ((c.u >> 16) & 1u)) >> 16);
}
__device__ __forceinline__ float bf2f(u16 b) {
  union { float f; unsigned u; } c; c.u = ((unsigned)b) << 16;
  return c.f;
}
__device__ __forceinline__ void gl_lds16(const u16* g, u16* l) {
  __builtin_amdgcn_global_load_lds(
      (const __attribute__((address_space(1))) void*)g,
      (__attribute__((address_space(3))) void*)l, 16, 0, 0);
}

// ---------------- cast fp32 -> bf16 ----------------
__global__ void castk(const float* __restrict__ src, u16* __restrict__ dst, int n) {
  int i = (blockIdx.x * 256 + threadIdx.x) * 4;
  if (i >= n) return;
  float4 v = *(const float4*)(src + i);
  dst[i + 0] = f2bf(v.x);
  dst[i + 1] = f2bf(v.y);
  dst[i + 2] = f2bf(v.z);
  dst[i + 3] = f2bf(v.w);
}

// ---------------- RoPE in-place on [rows, HD] bf16 ----------------
__global__ void ropek(u16* __restrict__ buf, int rows) {
  int idx = blockIdx.x * 256 + threadIdx.x;
  if (idx >= rows * 64) return;
  int r = idx >> 6, i = idx & 63;
  int t = r & (T_SEQ - 1);
  float inv = expf(-0.215867352496f * (float)i);  // 1e6^(-i/64)
  float ang = (float)t * inv;
  float c = cosf(ang), s = sinf(ang);
  size_t base = (size_t)r * HD + i;
  float x1 = bf2f(buf[base]), x2 = bf2f(buf[base + 64]);
  buf[base]      = f2bf(x1 * c - x2 * s);
  buf[base + 64] = f2bf(x2 * c + x1 * s);
}

// ---------------- GEMM: C[M,N] = A[M,K] @ Bm[N,K]^T  (bf16 in, MFMA) -------
// MODE 0: fp32 plain row-major out
// MODE 1: bf16 out scattered to [B, n_heads, T, HD]   (scaled)
// MODE 2: bf16 out scattered to [B, n_heads, HD, T]   (V transposed)
template <int MODE>
__global__ __launch_bounds__(256) void gemm_bt(
    const u16* __restrict__ A, const u16* __restrict__ Bm, void* __restrict__ Out,
    int M, int N, int K, int n_heads, float oscale) {
  __shared__ __align__(16) u16 As[128 * 32];
  __shared__ __align__(16) u16 Bs[128 * 32];
  const int tid = threadIdx.x;
  const int w = tid >> 6, l = tid & 63;
  const int lm = l & 15, q = l >> 4;
  const int m0 = blockIdx.y * 128, n0 = blockIdx.x * 128;
  const int mq = w & 1, nq = w >> 1;
  const u16* Ab = A + (size_t)m0 * K;
  const u16* Bb = Bm + (size_t)n0 * K;

  f32x4 acc[4][4] = {};

  for (int k0 = 0; k0 < K; k0 += 32) {
#pragma unroll
    for (int c = 0; c < 2; ++c) {
      int s = c * 256 + w * 64 + l;  // 16B slot id; row = s>>2, kq = s&3
      int row = s >> 2, kq = s & 3;
      gl_lds16(Ab + (size_t)row * K + k0 + kq * 8, As + s * 8);
      gl_lds16(Bb + (size_t)row * K + k0 + kq * 8, Bs + s * 8);
    }
    __syncthreads();
    short8 af[4], bf[4];
#pragma unroll
    for (int i = 0; i < 4; ++i) {
      af[i] = *(const short8*)(As + (mq * 64 + i * 16 + lm) * 32 + q * 8);
      bf[i] = *(const short8*)(Bs + (nq * 64 + i * 16 + lm) * 32 + q * 8);
    }
#pragma unroll
    for (int i = 0; i < 4; ++i)
#pragma unroll
      for (int j = 0; j < 4; ++j)
        acc[i][j] = __builtin_amdgcn_mfma_f32_16x16x32_bf16(af[i], bf[j], acc[i][j], 0, 0, 0);
    __syncthreads();
  }

#pragma unroll
  for (int i = 0; i < 4; ++i)
#pragma unroll
    for (int j = 0; j < 4; ++j)
#pragma unroll
      for (int r = 0; r < 4; ++r) {
        int m = m0 + mq * 64 + i * 16 + q * 4 + r;
        int n = n0 + nq * 64 + j * 16 + lm;
        float v = acc[i][j][r] * oscale;
        if constexpr (MODE == 0) {
          ((float*)Out)[(size_t)m * N + n] = v;
        } else {
          int b = m >> 11, t = m & (T_SEQ - 1);
          int h = n >> 7, d = n & (HD - 1);
          if constexpr (MODE == 1)
            ((u16*)Out)[(((size_t)(b * n_heads + h)) * T_SEQ + t) * HD + d] = f2bf(v);
          else
            ((u16*)Out)[(((size_t)(b * n_heads + h)) * HD + d) * T_SEQ + t] = f2bf(v);
        }
      }
}

// ---------------- flash attention v2 ----------------
// S^T orientation: mfma(k_frag, q_frag) -> C[s][qrow]; softmax reduction is
// in-register (16 vals/lane) + 2 shfl_xor. No __syncthreads anywhere.
// Block: 256 thr = 4 waves x 32 qrows = 128 qrows/tile; each block does the
// tile pair {15-p, p} -> 32-34 steps/wave, 256 blocks (1/CU), uniform.
// Q:[B,NH,T,HD] (pre-scaled by 1/sqrt(128)*log2e)  K:[B,NKV,T,HD]  V:[B,NKV,HD,T]
#define PSTRIDE 72
__global__ __launch_bounds__(256, 2) void attnk(
    const u16* __restrict__ Q, const u16* __restrict__ Kh,
    const u16* __restrict__ Vt, u16* __restrict__ Oa) {
  __shared__ __align__(16) u16 Pl[4][32 * PSTRIDE];
  const int tid = threadIdx.x;
  const int w = tid >> 6, l = tid & 63, lm = l & 15, q = l >> 4;
  const int bh = blockIdx.y, b = bh >> 4, h = bh & 15, kvh = h >> 2;
  const u16* Kb = Kh + ((size_t)(b * NKV + kvh)) * T_SEQ * HD;
  const u16* Vb = Vt + ((size_t)(b * NKV + kvh)) * HD * T_SEQ;
  u16* Pw = Pl[w];
  const int p = blockIdx.x;  // 0..7
  const int bsl = (l & 48) | ((l & 48) >> 2);  // broadcast src lane base: 16q+4q

#pragma unroll 1
  for (int half = 0; half < 2; ++half) {
    const int tile = half ? p : (15 - p);  // heavy tile first
    const int wbase = tile * 128 + w * 32;
    const u16* Qb = Q + (((size_t)(b * NHEAD + h)) * T_SEQ + wbase) * HD;

    short8 qa[2][4];
#pragma unroll
    for (int nt2 = 0; nt2 < 2; ++nt2)
#pragma unroll
      for (int ks = 0; ks < 4; ++ks)
        qa[nt2][ks] = *(const short8*)(Qb + (size_t)(nt2 * 16 + lm) * HD + ks * 32 + q * 8);

    float m_i[2] = {NEGBIG, NEGBIG}, l_i[2] = {0.f, 0.f};
    f32x4 oacc[2][8] = {};
    const int nst = (wbase >> 6) + 1;

    for (int st = 0; st < nst; ++st) {
      const int s0 = st * 64;
      f32x4 sacc[4][2] = {};
#pragma unroll
      for (int ks = 0; ks < 4; ++ks)
#pragma unroll
        for (int nt = 0; nt < 4; ++nt) {
          short8 kb = *(const short8*)(Kb + (size_t)(s0 + nt * 16 + lm) * HD + ks * 32 + q * 8);
          sacc[nt][0] = __builtin_amdgcn_mfma_f32_16x16x32_bf16(kb, qa[0][ks], sacc[nt][0], 0, 0, 0);
          sacc[nt][1] = __builtin_amdgcn_mfma_f32_16x16x32_bf16(kb, qa[1][ks], sacc[nt][1], 0, 0, 0);
        }

      float al[2];
#pragma unroll
      for (int nt2 = 0; nt2 < 2; ++nt2) {
        const int t_abs = wbase + nt2 * 16 + lm;
        float mx = m_i[nt2];
        float pe[4][4];
#pragma unroll
        for (int nt = 0; nt < 4; ++nt)
#pragma unroll
          for (int j = 0; j < 4; ++j) {
            int s_abs = s0 + nt * 16 + q * 4 + j;
            float v = (s_abs > t_abs) ? NEGBIG : sacc[nt][nt2][j];
            pe[nt][j] = v;
            mx = fmaxf(mx, v);
          }
        mx = fmaxf(mx, __shfl_xor(mx, 16, 64));
        mx = fmaxf(mx, __shfl_xor(mx, 32, 64));
        al[nt2] = exp2f(m_i[nt2] - mx);
        float sum = 0.f;
#pragma unroll
        for (int nt = 0; nt < 4; ++nt) {
          u16 pk[4];
#pragma unroll
          for (int j = 0; j < 4; ++j) {
            float e = exp2f(pe[nt][j] - mx);
            sum += e;
            pk[j] = f2bf(e);
          }
          *(u64*)(Pw + (nt2 * 16 + lm) * PSTRIDE + nt * 16 + q * 4) =
              (u64)pk[0] | ((u64)pk[1] << 16) | ((u64)pk[2] << 32) | ((u64)pk[3] << 48);
        }
        sum += __shfl_xor(sum, 16, 64);
        sum += __shfl_xor(sum, 32, 64);
        m_i[nt2] = mx;
        l_i[nt2] = l_i[nt2] * al[nt2] + sum;
      }

      // rescale O by alpha (broadcast alpha[qrow] to oacc layout)
#pragma unroll
      for (int mt = 0; mt < 2; ++mt)
#pragma unroll
        for (int j = 0; j < 4; ++j) {
          float a = __shfl(al[mt], bsl + j, 64);
#pragma unroll
          for (int nt8 = 0; nt8 < 8; ++nt8) oacc[mt][nt8][j] *= a;
        }

      // pin compile-time order: P LDS-writes above must precede PV LDS-reads.
      // (HW DS execution is in-order per wave; this blocks compiler reorder.)
      asm volatile("" ::: "memory");

      // PV
#pragma unroll
      for (int ks = 0; ks < 2; ++ks) {
        short8 pa0 = *(const short8*)(Pw + lm * PSTRIDE + ks * 32 + q * 8);
        short8 pa1 = *(const short8*)(Pw + (16 + lm) * PSTRIDE + ks * 32 + q * 8);
#pragma unroll
        for (int nt8 = 0; nt8 < 8; ++nt8) {
          short8 vb = *(const short8*)(Vb + (size_t)(nt8 * 16 + lm) * T_SEQ + s0 + ks * 32 + q * 8);
          oacc[0][nt8] = __builtin_amdgcn_mfma_f32_16x16x32_bf16(pa0, vb, oacc[0][nt8], 0, 0, 0);
          oacc[1][nt8] = __builtin_amdgcn_mfma_f32_16x16x32_bf16(pa1, vb, oacc[1][nt8], 0, 0, 0);
        }
      }
    }

    // epilogue: normalize by l and store bf16 [B, T, NH*HD]
#pragma unroll
    for (int mt = 0; mt < 2; ++mt)
#pragma unroll
      for (int j = 0; j < 4; ++j) {
        float li = __shfl(l_i[mt], bsl + j, 64);
        float inv = 1.0f / li;
        int t = wbase + mt * 16 + q * 4 + j;
#pragma unroll
        for (int nt8 = 0; nt8 < 8; ++nt8)
          Oa[((size_t)(b * T_SEQ + t)) * (NHEAD * HD) + h * HD + nt8 * 16 + lm] =
              f2bf(oacc[mt][nt8][j] * inv);
      }
  }
}

extern "C" void kernel_launch(void* const* d_in, const int* in_sizes, int n_in,
                              void* d_out, int out_size, void* d_ws, size_t ws_size,
                              hipStream_t stream) {
  const float* x  = (const float*)d_in[0];
  const float* wq = (const float*)d_in[1];
  const float* wk = (const float*)d_in[2];
  const float* wv = (const float*)d_in[3];
  const float* wo = (const float*)d_in[4];
  float* out = (float*)d_out;

  u16* ws  = (u16*)d_ws;
  u16* xb  = ws;                      // 8M elems  (x bf16)  [later: attn out]
  u16* wqb = xb  + (8u << 20);        // 4M
  u16* wkb = wqb + (4u << 20);        // 1M
  u16* wvb = wkb + (1u << 20);        // 1M
  u16* wob = wvb + (1u << 20);        // 4M
  u16* Qb  = wob + (4u << 20);        // 8M
  u16* Kb  = Qb  + (8u << 20);        // 2M
  u16* Vtb = Kb  + (2u << 20);        // 2M
  u16* Ab  = xb;                      // alias: 8M  (total 30M elems = 60 MB)

  castk<<<8192, 256, 0, stream>>>(x,  xb,  8 << 20);
  castk<<<4096, 256, 0, stream>>>(wq, wqb, 4 << 20);
  castk<<<1024, 256, 0, stream>>>(wk, wkb, 1 << 20);
  castk<<<1024, 256, 0, stream>>>(wv, wvb, 1 << 20);
  castk<<<4096, 256, 0, stream>>>(wo, wob, 4 << 20);

  // projections; Q pre-scaled by 1/sqrt(128)*log2(e) for exp2-domain softmax
  const float qscale = 0.088388347646f * 1.442695040889f;
  gemm_bt<1><<<dim3(16, 32), 256, 0, stream>>>(xb, wqb, Qb,  4096, 2048, 2048, NHEAD, qscale);
  gemm_bt<1><<<dim3(4, 32),  256, 0, stream>>>(xb, wkb, Kb,  4096, 512,  2048, NKV, 1.0f);
  gemm_bt<2><<<dim3(4, 32),  256, 0, stream>>>(xb, wvb, Vtb, 4096, 512,  2048, NKV, 1.0f);

  // RoPE on Q and K (linear, commutes with Q pre-scale)
  ropek<<<16384, 256, 0, stream>>>(Qb, 2 * NHEAD * T_SEQ);
  ropek<<<4096,  256, 0, stream>>>(Kb, 2 * NKV * T_SEQ);

  // attention: grid (8 tile-pairs, B*NHEAD = 32)
  attnk<<<dim3(8, 32), 256, 0, stream>>>(Qb, Kb, Vtb, Ab);

  // output projection -> fp32 d_out
  gemm_bt<0><<<dim3(16, 32), 256, 0, stream>>>(Ab, wob, out, 4096, 2048, 2048, 0, 1.0f);
}